// Round 12
// baseline (145.306 us; speedup 1.0000x reference)
//
#include <hip/hip_runtime.h>
#include <cstdint>
#include <cstddef>

// Problem: B=32, S=2048, D=512, H=512
//   sb[b,h]   = state @ W1[:D]
//   h         = tanh(tanh(sb + input@W1[D:]))   <-- DOUBLE tanh (reference quirk)
//   logit[b,s]= sum_h h * w2[h]  - 1e30*(1-mask)
//   p = softmax over S;  pooled[b,d] = sum_s p*input
// Outputs: pooled (16384 f32) ++ logit (65536 f32)
//
// r12 architecture: NO bf16 input copy (r11 post-mortem: cvt pass latency-bound at
// 1.8 TB/s, ~70us). k1 reg-stages fp32 A with in-register v_cvt_pk_bf16_f32; k3
// reads fp32 directly (L3-warm after k1).

#define NEG_BIG 1e30f

typedef __attribute__((ext_vector_type(8))) short short8_t;   // 8 x bf16
typedef __attribute__((ext_vector_type(4))) float f32x4;

__device__ inline unsigned short f2bf(float f){
  union { float f; unsigned int u; } v; v.f = f;
  unsigned int r = v.u + 0x7fffu + ((v.u >> 16) & 1u);   // RNE
  return (unsigned short)(r >> 16);
}
// tanh via 1 - 2/(1+e^{2x}): exp overflow -> inf -> rcp -> 0 -> +1; underflow -> -1.
__device__ inline float tanh_cheap(float x){
  return 1.0f - 2.0f*__builtin_amdgcn_rcpf(1.0f + __expf(2.0f*x));
}

typedef __attribute__((address_space(1))) const unsigned int g_u32;
typedef __attribute__((address_space(3))) unsigned int l_u32;
__device__ inline void gload16(const unsigned short* g, unsigned short* l){
  __builtin_amdgcn_global_load_lds((g_u32*)g, (l_u32*)l, 16, 0, 0);
}

// ---------------------------------------------------------------- K0: prep (tiny)
// blocks 0..63   : w1xt[h][k] = bf16(W1[512+k][h])   (transpose)
// blocks 64..319 : sbp[ds][b][h] partial state@W1s   (d-split: 8 slices x 32 b)
__global__ __launch_bounds__(256) void k0_prep(const float* __restrict__ state,
                                               const float* __restrict__ W1,
                                               float* __restrict__ sbp,
                                               unsigned short* __restrict__ w1xt){
  const int bid = blockIdx.x, t = threadIdx.x;
  if (bid < 64) {
    const int q  = bid;
    const int k0 = (q >> 3) * 64, h0 = (q & 7) * 64;
    __shared__ float tile[64][65];
    const int c = t & 63, r0 = t >> 6;
    #pragma unroll
    for (int i = 0; i < 16; ++i){
      int r = r0 + 4*i;
      tile[r][c] = W1[(size_t)(512 + k0 + r)*512 + h0 + c];
    }
    __syncthreads();
    #pragma unroll
    for (int i = 0; i < 16; ++i){
      int r = r0 + 4*i;
      w1xt[(size_t)(h0 + r)*512 + k0 + c] = f2bf(tile[c][r]);
    }
  } else {
    const int idx = bid - 64;               // 0..255
    const int b = idx >> 3, ds = idx & 7;
    __shared__ float stl[64];
    if (t < 64) stl[t] = state[b*512 + ds*64 + t];
    __syncthreads();
    float acc0 = 0.f, acc1 = 0.f;
    #pragma unroll 8
    for (int i = 0; i < 64; ++i){
      const float w = stl[i];
      acc0 += w * W1[(size_t)(ds*64 + i)*512 + t];
      acc1 += w * W1[(size_t)(ds*64 + i)*512 + t + 256];
    }
    sbp[(size_t)(ds*32 + b)*512 + t]       = acc0;
    sbp[(size_t)(ds*32 + b)*512 + t + 256] = acc1;
  }
}

// ---------------------------------------------------------------- K1: 256x256 8-phase GEMM, fp32-A reg-staged
// Same verified r10 schedule/regions/reads. A-side: gload_lds replaced by
//   ALOAD (8x float4, 4-rows-x-256B coalesced) at p0/p4  ->  AWRITE (cvt_pk + 8x
//   ds_write_b64) at p3/p7 — the exact phase slots where STAGE_P(A) sat, so the
//   region-free windows (buf0-A after p2-end, buf1-A after p6-end) are unchanged.
// LDS layout identical to r10 (phys chunk = logical ^ (row&7)) -> READ side untouched.
// B-side: gload_lds with inverse-swizzled source (rule #21), staged p0/p4.
// vmcnt: A-loads are plain loads (compiler auto-waits; A issued before B so the
// wait leaves B in flight). Manual gates: vmcnt(0) post-MFMA at p3 (B(kt+1) lands
// before p4 reads) and at p7, i<3 (B(kt+2) before next-iter p0). lgkmcnt(0) before
// the p3/p7 barrier makes the ds_writes cross-wave visible.
__global__ __launch_bounds__(512, 1) void k1_gemm_8ph(const float* __restrict__ input,
                                                      const unsigned short* __restrict__ w1xt,
                                                      const float* __restrict__ sbp,
                                                      const float* __restrict__ w2,
                                                      float* __restrict__ plog){
  __shared__ unsigned short lds[65536];   // 128 KB

  const int orig = blockIdx.x;            // 512 blocks, bijective XCD swizzle (512%8==0)
  const int xcd = orig & 7, qq = orig >> 3;
  const int mtile = xcd*32 + (qq >> 1);
  const int nt = qq & 1;                  // nt 0/1 of same mtile adjacent on same XCD -> A L2 reuse
  const int m0 = mtile*256, n0 = nt*256;
  const int b = m0 >> 11;

  const int t = threadIdx.x;
  const int lane = t & 63, wid = t >> 6;
  const int wr = wid >> 2, wcn = wid & 3;
  const int lr = lane & 15, kg = lane >> 4;
  const int l7 = lr & 7;

  // --- B stage source (inverse-swizzled chunks)
  const int sl8 = ((lane & 7) ^ ((lane >> 3) & 7)) * 8;
  const unsigned short* gB = w1xt + (size_t)(n0 + wid*16 + (lane>>3))*512 + sl8;

  // --- A reg-stage mapping: load j covers rows wid*32 + j*4 + (lane>>4), floats (lane&15)*4..+3
  const int as_row0 = wid*32 + (lane >> 4);
  const float* gAf = input + (size_t)(m0 + as_row0)*512 + (lane & 15)*4;
  const int lcA  = (lane & 15) >> 1;      // logical 8-col bf16 chunk
  const int subA = (lane & 1) * 4;        // elems within chunk

  // --- fragment read bases (elems); unchanged from r10
  const unsigned aBase = (unsigned)((wr*128 + lr)*64);
  const unsigned bBase = 16384u + (unsigned)((wcn*64 + lr)*64);
  const unsigned swz0 = (unsigned)(((0*4 + kg) ^ l7) * 8);
  const unsigned swz1 = (unsigned)(((1*4 + kg) ^ l7) * 8);

  f32x4 acc[8][4];
  #pragma unroll
  for (int mi = 0; mi < 8; ++mi)
    #pragma unroll
    for (int ni = 0; ni < 4; ++ni) acc[mi][ni] = (f32x4){0.f,0.f,0.f,0.f};

  short8_t af[4][2], bf[2][2];
  float4 av[8];

#define STAGE_B(KT) do{ \
    const unsigned short* gs0_ = gB + (KT)*64; \
    unsigned short* ds0_ = &lds[(unsigned)(((KT)&1)*32768 + 16384 + wid*1024)]; \
    gload16(gs0_,           ds0_); \
    gload16(gs0_ + 8*512,   ds0_ + 512); \
    gload16(gs0_ + 128*512, ds0_ + 8192); \
    gload16(gs0_ + 136*512, ds0_ + 8704); }while(0)

#define ALOAD(KT) do{ _Pragma("unroll") for (int j = 0; j < 8; ++j) \
    av[j] = *reinterpret_cast<const float4*>(gAf + (size_t)j*4*512 + (KT)*64); }while(0)

#define AWRITE(BO) do{ \
    _Pragma("unroll") for (int j = 0; j < 8; ++j){ \
      const int rj = as_row0 + j*4; \
      unsigned int d0_, d1_; \
      asm("v_cvt_pk_bf16_f32 %0, %1, %2" : "=v"(d0_) : "v"(av[j].x), "v"(av[j].y)); \
      asm("v_cvt_pk_bf16_f32 %0, %1, %2" : "=v"(d1_) : "v"(av[j].z), "v"(av[j].w)); \
      uint2 w_; w_.x = d0_; w_.y = d1_; \
      *reinterpret_cast<uint2*>(&lds[(BO) + (unsigned)(rj*64 + ((lcA ^ (rj & 7))*8) + subA)]) = w_; \
    } }while(0)

#define READ_A(mh, bo) do{ _Pragma("unroll") for (int mi = 0; mi < 4; ++mi){ \
    af[mi][0] = *(const short8_t*)&lds[(bo) + aBase + (unsigned)((mh)*4+mi)*1024 + swz0]; \
    af[mi][1] = *(const short8_t*)&lds[(bo) + aBase + (unsigned)((mh)*4+mi)*1024 + swz1]; } }while(0)

#define READ_B(nh, bo) do{ _Pragma("unroll") for (int ni = 0; ni < 2; ++ni){ \
    bf[ni][0] = *(const short8_t*)&lds[(bo) + bBase + (unsigned)((nh)*2+ni)*1024 + swz0]; \
    bf[ni][1] = *(const short8_t*)&lds[(bo) + bBase + (unsigned)((nh)*2+ni)*1024 + swz1]; } }while(0)

#define MFMA16(mh, nh) do{ \
    __builtin_amdgcn_s_setprio(1); \
    _Pragma("unroll") for (int mi = 0; mi < 4; ++mi) \
      _Pragma("unroll") for (int ni = 0; ni < 2; ++ni){ \
        acc[(mh)*4+mi][(nh)*2+ni] = __builtin_amdgcn_mfma_f32_16x16x32_bf16(af[mi][0], bf[ni][0], acc[(mh)*4+mi][(nh)*2+ni], 0,0,0); \
        acc[(mh)*4+mi][(nh)*2+ni] = __builtin_amdgcn_mfma_f32_16x16x32_bf16(af[mi][1], bf[ni][1], acc[(mh)*4+mi][(nh)*2+ni], 0,0,0); } \
    __builtin_amdgcn_s_setprio(0); }while(0)

  // prologue: A(0)->buf0, A(1)->buf1 (reg->cvt->LDS), B(0) staged async
  ALOAD(0);
  __builtin_amdgcn_sched_barrier(0);
  STAGE_B(0);
  AWRITE(0);          // compiler waits av (A issued first -> B(0) stays in flight)
  ALOAD(1);
  __builtin_amdgcn_sched_barrier(0);
  AWRITE(32768);      // newest loads -> compiler drains all (prologue; fine)
  asm volatile("s_waitcnt vmcnt(0) lgkmcnt(0)" ::: "memory");
  __builtin_amdgcn_s_barrier();

  #pragma unroll
  for (int i = 0; i < 4; ++i){
    #pragma unroll
    for (int p = 0; p < 8; ++p){
      const int kt = 2*i + (p>>2);
      const unsigned bo = (unsigned)((kt & 1) * 32768);
      const int q = p & 3;
      // --- ds-load register subtiles
      if (q == 0){ READ_A(0, bo); READ_B(0, bo); }
      else if (q == 1){ READ_B(1, bo); }
      else if (q == 2){ READ_A(1, bo); READ_B(0, bo); }
      else { READ_B(1, bo); }
      // --- A-load / B-stage / A-write schedule (region-free windows as r10)
      if (p == 0){
        if (i < 3){ ALOAD(2*i+2); __builtin_amdgcn_sched_barrier(0); }
        STAGE_B(2*i+1);
      } else if (p == 3){
        if (i < 3){ AWRITE(0); }                      // buf0-A free since p2-end
        asm volatile("s_waitcnt lgkmcnt(0)" ::: "memory");  // ds_write visible pre-barrier
      } else if (p == 4){
        if (i < 3){ ALOAD(2*i+3); __builtin_amdgcn_sched_barrier(0); STAGE_B(2*i+2); }
      } else if (p == 7){
        if (i < 3){ AWRITE(32768);                    // buf1-A free since p6-end
                    asm volatile("s_waitcnt lgkmcnt(0)" ::: "memory"); }
      }
      __builtin_amdgcn_s_barrier();
      asm volatile("s_waitcnt lgkmcnt(0)" ::: "memory");
      __builtin_amdgcn_sched_barrier(0);
      MFMA16(q >> 1, q & 1);
      // --- gates: B must land before its buffer is read
      if (p == 3){
        asm volatile("s_waitcnt vmcnt(0)" ::: "memory");       // B(2i+1) before p4 reads
      } else if (p == 7 && i < 3){
        asm volatile("s_waitcnt vmcnt(0)" ::: "memory");       // B(2i+2) before next p0 reads
      }
      __builtin_amdgcn_s_barrier();
    }
  }
#undef STAGE_B
#undef ALOAD
#undef AWRITE
#undef READ_A
#undef READ_B
#undef MFMA16

  // epilogue: tanh(tanh(acc + sb)) * w2, reduce over this block's 256 h-cols
  float w2v[4], sbv[4];
  #pragma unroll
  for (int ni = 0; ni < 4; ++ni){
    const int h = n0 + wcn*64 + ni*16 + lr;
    w2v[ni] = w2[h];
    float s = 0.f;
    #pragma unroll
    for (int ds = 0; ds < 8; ++ds) s += sbp[(size_t)(ds*32 + b)*512 + h];
    sbv[ni] = s;
  }
  float* red = reinterpret_cast<float*>(&lds[0]);   // 1024 floats (post-barrier reuse)
  #pragma unroll
  for (int mi = 0; mi < 8; ++mi){
    #pragma unroll
    for (int j = 0; j < 4; ++j){
      float v = 0.f;
      #pragma unroll
      for (int ni = 0; ni < 4; ++ni)
        v += tanh_cheap(tanh_cheap(acc[mi][ni][j] + sbv[ni])) * w2v[ni];
      v += __shfl_xor(v, 1); v += __shfl_xor(v, 2);
      v += __shfl_xor(v, 4); v += __shfl_xor(v, 8);   // sum 16 cols
      if (lr == 0)
        red[wcn*256 + wr*128 + mi*16 + kg*4 + j] = v; // C/D row=(lane>>4)*4+j
    }
  }
  __syncthreads();
  if (t < 256)
    plog[(size_t)nt*65536 + m0 + t] = red[t] + red[256+t] + red[512+t] + red[768+t];
}

// ---------------------------------------------------------------- K2: softmax stats
__global__ __launch_bounds__(256) void k2_softmax(const float* __restrict__ plog,
                                                  const float* __restrict__ mask,
                                                  float* __restrict__ out_logit,
                                                  float* __restrict__ mz){
  const int b = blockIdx.x, t = threadIdx.x;
  float l[8]; float mx = -3.4e38f;
  #pragma unroll
  for (int i = 0; i < 8; ++i){
    const size_t idx = (size_t)b*2048 + t + i*256;
    float v = plog[idx] + plog[65536 + idx];
    v -= NEG_BIG * (1.0f - mask[idx]);
    l[i] = v;
    out_logit[idx] = v;
    mx = fmaxf(mx, v);
  }
  __shared__ float red[8];
  const int wid = t >> 6, lane = t & 63;
  #pragma unroll
  for (int off = 1; off < 64; off <<= 1) mx = fmaxf(mx, __shfl_xor(mx, off));
  if (lane == 0) red[wid] = mx;
  __syncthreads();
  mx = fmaxf(fmaxf(red[0], red[1]), fmaxf(red[2], red[3]));
  float zs = 0.f;
  #pragma unroll
  for (int i = 0; i < 8; ++i) zs += __expf(l[i] - mx);
  #pragma unroll
  for (int off = 1; off < 64; off <<= 1) zs += __shfl_xor(zs, off);
  if (lane == 0) red[4 + wid] = zs;
  __syncthreads();
  if (t == 0){ mz[b*2] = mx; mz[b*2+1] = red[4]+red[5]+red[6]+red[7]; }
}

// ---------------------------------------------------------------- K3: pooled partials (fp32 input, float4/thread)
__global__ __launch_bounds__(256) void k3_pool(const float* __restrict__ input,
                                               const float* __restrict__ logit,
                                               const float* __restrict__ mz,
                                               float* __restrict__ pool){
  const int b = blockIdx.x >> 4, sc = blockIdx.x & 15;
  const int t = threadIdx.x;
  __shared__ float p[128];
  const float m = mz[b*2], invZ = 1.0f / mz[b*2+1];
  if (t < 128) p[t] = __expf(logit[(size_t)b*2048 + sc*128 + t] - m) * invZ;
  __syncthreads();
  const int half = t >> 7, cw = t & 127;
  float a0=0.f,a1=0.f,a2=0.f,a3=0.f;
  const float* base = input + ((size_t)b*2048 + sc*128 + half)*512 + cw*4;
  #pragma unroll 4
  for (int i = 0; i < 64; ++i){
    const float4 v = *reinterpret_cast<const float4*>(base + (size_t)i*1024);
    const float pv = p[half + 2*i];
    a0 += pv*v.x; a1 += pv*v.y; a2 += pv*v.z; a3 += pv*v.w;
  }
  float4 o = {a0,a1,a2,a3};
  *reinterpret_cast<float4*>(pool + (size_t)blockIdx.x*1024 + half*512 + cw*4) = o;
}

// ---------------------------------------------------------------- K4: reduce partials
__global__ __launch_bounds__(256) void k4_reduce(const float* __restrict__ pool,
                                                 float* __restrict__ out_pooled){
  const int tg = blockIdx.x*256 + threadIdx.x;  // 0..16383
  const int b = tg >> 9, d = tg & 511;
  float s = 0.f;
  #pragma unroll
  for (int c = 0; c < 32; ++c) s += pool[((size_t)b*32 + c)*512 + d];
  out_pooled[tg] = s;
}

// ---------------------------------------------------------------- launch
extern "C" void kernel_launch(void* const* d_in, const int* in_sizes, int n_in,
                              void* d_out, int out_size, void* d_ws, size_t ws_size,
                              hipStream_t stream){
  const float* input = (const float*)d_in[0];
  const float* state = (const float*)d_in[1];
  const float* mask  = (const float*)d_in[2];
  const float* W1    = (const float*)d_in[3];
  const float* w2    = (const float*)d_in[4];

  float* out_pooled = (float*)d_out;
  float* out_logit  = (float*)d_out + 16384;

  char* ws = (char*)d_ws;
  float*          sbp  = (float*)(ws);                   // 512 KB
  unsigned short* w1xt = (unsigned short*)(ws + 524288); // 512 KB
  float*          plog = (float*)(ws + 1048576);         // 512 KB (2 partials)
  float*          mz   = (float*)(ws + 1572864);         // 256 B
  float*          pool = (float*)(ws + 1573120);         // 2 MB
  (void)ws_size; (void)in_sizes; (void)n_in; (void)out_size;

  k0_prep    <<<320, 256, 0, stream>>>(state, W1, sbp, w1xt);
  k1_gemm_8ph<<<512, 512, 0, stream>>>(input, w1xt, sbp, w2, plog);
  k2_softmax <<<32,  256, 0, stream>>>(plog, mask, out_logit, mz);
  k3_pool    <<<512, 256, 0, stream>>>(input, out_logit, mz, pool);
  k4_reduce  <<<64,  256, 0, stream>>>(pool, out_pooled);
}

// Round 13
// 117.195 us; speedup vs baseline: 1.2399x; 1.2399x over previous
//
#include <hip/hip_runtime.h>
#include <cstdint>
#include <cstddef>

// Problem: B=32, S=2048, D=512, H=512
//   sb[b,h]   = state @ W1[:D]
//   h         = tanh(tanh(sb + input@W1[D:]))   <-- DOUBLE tanh (reference quirk)
//   logit[b,s]= sum_h h * w2[h]  - 1e30*(1-mask)
//   p = softmax over S;  pooled[b,d] = sum_s p*input
// Outputs: pooled (16384 f32) ++ logit (65536 f32)
//
// r13: revert to r11 architecture (verified 116us; k1~23us). ONLY change: cvt branch
// gets forced 8-deep MLP (r12 post-mortem: VGPR=28 proved the compiler serialized
// loads; sched_barrier(0) + launch_bounds(256,1) force the batch live in regs).

#define NEG_BIG 1e30f

typedef __attribute__((ext_vector_type(8))) short short8_t;   // 8 x bf16
typedef __attribute__((ext_vector_type(4))) float f32x4;

__device__ inline unsigned short f2bf(float f){
  union { float f; unsigned int u; } v; v.f = f;
  unsigned int r = v.u + 0x7fffu + ((v.u >> 16) & 1u);   // RNE
  return (unsigned short)(r >> 16);
}
__device__ inline float bf2f(unsigned int lo16){
  union { unsigned int u; float f; } v; v.u = lo16 << 16; return v.f;
}
// tanh via 1 - 2/(1+e^{2x}): exp overflow -> inf -> rcp -> 0 -> +1; underflow -> -1.
__device__ inline float tanh_cheap(float x){
  return 1.0f - 2.0f*__builtin_amdgcn_rcpf(1.0f + __expf(2.0f*x));
}

typedef __attribute__((address_space(1))) const unsigned int g_u32;
typedef __attribute__((address_space(3))) unsigned int l_u32;
__device__ inline void gload16(const unsigned short* g, unsigned short* l){
  __builtin_amdgcn_global_load_lds((g_u32*)g, (l_u32*)l, 16, 0, 0);
}

// ---------------------------------------------------------------- K0: merged prologue
// blocks [0, ncvt)           : inb = bf16(input) — FORCED 8-deep MLP x 2 batches
// blocks [ncvt, ncvt+64)     : w1xt[h][k] = bf16(W1[512+k][h])  (transpose)
// blocks [ncvt+64, ncvt+320) : sbp[ds][b][h] partial state@W1s  (hides under cvt)
__global__ __launch_bounds__(256, 1) void k0_all(const float* __restrict__ input,
                                                 const float* __restrict__ state,
                                                 const float* __restrict__ W1,
                                                 unsigned short* __restrict__ inb,
                                                 float* __restrict__ sbp,
                                                 unsigned short* __restrict__ w1xt,
                                                 int ncvt){
  const int bid = blockIdx.x, t = threadIdx.x;
  if (bid < ncvt) {
    const int tid = bid*256 + t;                  // 2048 blocks -> 524288 threads
    const float4* in4 = (const float4*)input;     // 8388608 float4 total
    ushort4* o4 = (ushort4*)inb;
    #pragma unroll
    for (int half = 0; half < 2; ++half){
      float4 v[8];
      #pragma unroll
      for (int j = 0; j < 8; ++j)
        v[j] = in4[(size_t)(half*8 + j)*524288 + tid];
      __builtin_amdgcn_sched_barrier(0);          // loads may NOT sink past here
      #pragma unroll
      for (int j = 0; j < 8; ++j){
        ushort4 o; o.x=f2bf(v[j].x); o.y=f2bf(v[j].y); o.z=f2bf(v[j].z); o.w=f2bf(v[j].w);
        o4[(size_t)(half*8 + j)*524288 + tid] = o;
      }
    }
  } else if (bid < ncvt + 64) {
    const int q  = bid - ncvt;
    const int k0 = (q >> 3) * 64, h0 = (q & 7) * 64;
    __shared__ float tile[64][65];
    const int c = t & 63, r0 = t >> 6;
    #pragma unroll
    for (int i = 0; i < 16; ++i){
      int r = r0 + 4*i;
      tile[r][c] = W1[(size_t)(512 + k0 + r)*512 + h0 + c];
    }
    __syncthreads();
    #pragma unroll
    for (int i = 0; i < 16; ++i){
      int r = r0 + 4*i;
      w1xt[(size_t)(h0 + r)*512 + k0 + c] = f2bf(tile[c][r]);
    }
  } else {
    const int idx = bid - ncvt - 64;        // 0..255
    const int b = idx >> 3, ds = idx & 7;
    __shared__ float stl[64];
    if (t < 64) stl[t] = state[b*512 + ds*64 + t];
    __syncthreads();
    float acc0 = 0.f, acc1 = 0.f;
    #pragma unroll 8
    for (int i = 0; i < 64; ++i){
      const float w = stl[i];
      acc0 += w * W1[(size_t)(ds*64 + i)*512 + t];
      acc1 += w * W1[(size_t)(ds*64 + i)*512 + t + 256];
    }
    sbp[(size_t)(ds*32 + b)*512 + t]       = acc0;
    sbp[(size_t)(ds*32 + b)*512 + t + 256] = acc1;
  }
}

// ---------------------------------------------------------------- K1: 256x256 8-phase GEMM
// (EXACT r10/r11 kernel — verified correct, ~23us)
// REGION READ TABLE: buf0-A free after p2-end, buf0-B after p3-end, buf1-A after p6-end,
// buf1-B after p7-end (prev iter). STAGE: p0:B(kt+1) | p3:A(kt+2) | p4:B(kt+2) | p7:A(kt+3).
// vmcnt(4) at p3/p7; tail vmcnt(0)@p3 of i=3.
// Swizzle: phys16Bchunk = logical ^ (row&7) via inverse-swizzled global src (rule #21).
__global__ __launch_bounds__(512, 1) void k1_gemm_8ph(const unsigned short* __restrict__ inb,
                                                      const unsigned short* __restrict__ w1xt,
                                                      const float* __restrict__ sbp,
                                                      const float* __restrict__ w2,
                                                      float* __restrict__ plog){
  __shared__ unsigned short lds[65536];   // 128 KB

  const int orig = blockIdx.x;            // 512 blocks, bijective XCD swizzle (512%8==0)
  const int xcd = orig & 7, qq = orig >> 3;
  const int mtile = xcd*32 + (qq >> 1);
  const int nt = qq & 1;
  const int m0 = mtile*256, n0 = nt*256;
  const int b = m0 >> 11;

  const int t = threadIdx.x;
  const int lane = t & 63, wid = t >> 6;
  const int wr = wid >> 2, wcn = wid & 3;
  const int lr = lane & 15, kg = lane >> 4;
  const int l7 = lr & 7;

  const int sl8 = ((lane & 7) ^ ((lane >> 3) & 7)) * 8;
  const unsigned short* gA = inb  + (size_t)(m0 + wid*16 + (lane>>3))*512 + sl8;
  const unsigned short* gB = w1xt + (size_t)(n0 + wid*16 + (lane>>3))*512 + sl8;

  const unsigned aBase = (unsigned)((wr*128 + lr)*64);
  const unsigned bBase = 16384u + (unsigned)((wcn*64 + lr)*64);
  const unsigned swz0 = (unsigned)(((0*4 + kg) ^ l7) * 8);   // ks=0
  const unsigned swz1 = (unsigned)(((1*4 + kg) ^ l7) * 8);   // ks=1

  f32x4 acc[8][4];
  #pragma unroll
  for (int mi = 0; mi < 8; ++mi)
    #pragma unroll
    for (int ni = 0; ni < 4; ++ni) acc[mi][ni] = (f32x4){0.f,0.f,0.f,0.f};

  short8_t af[4][2], bf[2][2];

#define STAGE_P(KT, PART) do{ \
    const unsigned short* gs_ = ((PART) < 2 ? gA : gB) + (size_t)((PART)&1)*128*512 + (KT)*64; \
    unsigned short* ds_ = &lds[(unsigned)(((KT)&1)*32768 + ((PART)>>1)*16384 + ((PART)&1)*8192 + wid*1024)]; \
    gload16(gs_,         ds_); \
    gload16(gs_ + 8*512, ds_ + 512); }while(0)

#define READ_A(mh, bo) do{ _Pragma("unroll") for (int mi = 0; mi < 4; ++mi){ \
    af[mi][0] = *(const short8_t*)&lds[(bo) + aBase + (unsigned)((mh)*4+mi)*1024 + swz0]; \
    af[mi][1] = *(const short8_t*)&lds[(bo) + aBase + (unsigned)((mh)*4+mi)*1024 + swz1]; } }while(0)

#define READ_B(nh, bo) do{ _Pragma("unroll") for (int ni = 0; ni < 2; ++ni){ \
    bf[ni][0] = *(const short8_t*)&lds[(bo) + bBase + (unsigned)((nh)*2+ni)*1024 + swz0]; \
    bf[ni][1] = *(const short8_t*)&lds[(bo) + bBase + (unsigned)((nh)*2+ni)*1024 + swz1]; } }while(0)

#define MFMA16(mh, nh) do{ \
    __builtin_amdgcn_s_setprio(1); \
    _Pragma("unroll") for (int mi = 0; mi < 4; ++mi) \
      _Pragma("unroll") for (int ni = 0; ni < 2; ++ni){ \
        acc[(mh)*4+mi][(nh)*2+ni] = __builtin_amdgcn_mfma_f32_16x16x32_bf16(af[mi][0], bf[ni][0], acc[(mh)*4+mi][(nh)*2+ni], 0,0,0); \
        acc[(mh)*4+mi][(nh)*2+ni] = __builtin_amdgcn_mfma_f32_16x16x32_bf16(af[mi][1], bf[ni][1], acc[(mh)*4+mi][(nh)*2+ni], 0,0,0); } \
    __builtin_amdgcn_s_setprio(0); }while(0)

  // prologue: A(0), B(0), A(1) = 12 loads; vmcnt(4) -> kt0 landed, A(1) in flight
  STAGE_P(0,0); STAGE_P(0,1); STAGE_P(0,2); STAGE_P(0,3);
  STAGE_P(1,0); STAGE_P(1,1);
  asm volatile("s_waitcnt vmcnt(4)" ::: "memory");
  __builtin_amdgcn_s_barrier();

  #pragma unroll
  for (int i = 0; i < 4; ++i){
    #pragma unroll
    for (int p = 0; p < 8; ++p){
      const int kt = 2*i + (p>>2);
      const unsigned bo = (unsigned)((kt & 1) * 32768);
      const int q = p & 3;
      if (q == 0){ READ_A(0, bo); READ_B(0, bo); }
      else if (q == 1){ READ_B(1, bo); }
      else if (q == 2){ READ_A(1, bo); READ_B(0, bo); }
      else { READ_B(1, bo); }
      if (p == 0){                  STAGE_P(2*i+1, 2); STAGE_P(2*i+1, 3); }   // B(kt+1)
      else if (p == 3){ if (i < 3){ STAGE_P(2*i+2, 0); STAGE_P(2*i+2, 1); } } // A(kt+2)
      else if (p == 4){ if (i < 3){ STAGE_P(2*i+2, 2); STAGE_P(2*i+2, 3); } } // B(kt+2)
      else if (p == 7){ if (i < 3){ STAGE_P(2*i+3, 0); STAGE_P(2*i+3, 1); } } // A(kt+3)
      __builtin_amdgcn_s_barrier();
      asm volatile("s_waitcnt lgkmcnt(0)" ::: "memory");
      __builtin_amdgcn_sched_barrier(0);
      MFMA16(q >> 1, q & 1);
      if (p == 3){
        if (i < 3) asm volatile("s_waitcnt vmcnt(4)" ::: "memory");
        else       asm volatile("s_waitcnt vmcnt(0)" ::: "memory");
      } else if (p == 7 && i < 3){
        asm volatile("s_waitcnt vmcnt(4)" ::: "memory");
      }
      __builtin_amdgcn_s_barrier();
    }
  }
#undef STAGE_P
#undef READ_A
#undef READ_B
#undef MFMA16

  // epilogue: tanh(tanh(acc + sb)) * w2, reduce over this block's 256 h-cols
  float w2v[4], sbv[4];
  #pragma unroll
  for (int ni = 0; ni < 4; ++ni){
    const int h = n0 + wcn*64 + ni*16 + lr;
    w2v[ni] = w2[h];
    float s = 0.f;
    #pragma unroll
    for (int ds = 0; ds < 8; ++ds) s += sbp[(size_t)(ds*32 + b)*512 + h];
    sbv[ni] = s;
  }
  float* red = reinterpret_cast<float*>(&lds[0]);   // 1024 floats (post-barrier reuse)
  #pragma unroll
  for (int mi = 0; mi < 8; ++mi){
    #pragma unroll
    for (int j = 0; j < 4; ++j){
      float v = 0.f;
      #pragma unroll
      for (int ni = 0; ni < 4; ++ni)
        v += tanh_cheap(tanh_cheap(acc[mi][ni][j] + sbv[ni])) * w2v[ni];
      v += __shfl_xor(v, 1); v += __shfl_xor(v, 2);
      v += __shfl_xor(v, 4); v += __shfl_xor(v, 8);   // sum 16 cols
      if (lr == 0)
        red[wcn*256 + wr*128 + mi*16 + kg*4 + j] = v; // C/D row=(lane>>4)*4+j
    }
  }
  __syncthreads();
  if (t < 256)
    plog[(size_t)nt*65536 + m0 + t] = red[t] + red[256+t] + red[512+t] + red[768+t];
}

// ---------------------------------------------------------------- K1 fallback (reg-staged, pad-72, 4 N-parts)
__global__ __launch_bounds__(256) void k1_gemm_fb(const float* __restrict__ input,
                                                  const unsigned short* __restrict__ w1xt,
                                                  const float* __restrict__ sbp,
                                                  const float* __restrict__ w2,
                                                  float* __restrict__ plog){
  __shared__ unsigned short lds_a[128][72];
  __shared__ unsigned short lds_b[128][72];
  const int orig = blockIdx.x;
  const int xcd  = orig & 7, slot = orig >> 3;
  const int mtile = xcd*64 + (slot >> 2);
  const int nt    = slot & 3;
  const int m0 = mtile * 128, n0 = nt * 128;
  const int b  = m0 >> 11;
  const int t = threadIdx.x;
  const int lane = t & 63, wid = t >> 6;
  const int wr = wid >> 1, wc = wid & 1;
  const int lr = lane & 15, kg = lane >> 4;
  f32x4 acc[4][4];
  #pragma unroll
  for (int mi = 0; mi < 4; ++mi)
    #pragma unroll
    for (int ni = 0; ni < 4; ++ni) acc[mi][ni] = (f32x4){0.f,0.f,0.f,0.f};
  const int ar0 = t >> 4, afo = t & 15;
  const int br0 = t >> 3, bho = t & 7;
  for (int kk = 0; kk < 512; kk += 64){
    #pragma unroll
    for (int rr = 0; rr < 8; ++rr){
      const int r = ar0 + rr*16;
      const float4 v = *reinterpret_cast<const float4*>(input + (size_t)(m0 + r)*512 + kk + afo*4);
      ushort4 bv; bv.x=f2bf(v.x); bv.y=f2bf(v.y); bv.z=f2bf(v.z); bv.w=f2bf(v.w);
      *reinterpret_cast<ushort4*>(&lds_a[r][afo*4]) = bv;
    }
    #pragma unroll
    for (int rr = 0; rr < 4; ++rr){
      const int r = br0 + rr*32;
      const uint4 v = *reinterpret_cast<const uint4*>(w1xt + (size_t)(n0 + r)*512 + kk + bho*8);
      *reinterpret_cast<uint4*>(&lds_b[r][bho*8]) = v;
    }
    __syncthreads();
    #pragma unroll
    for (int ks = 0; ks < 64; ks += 32){
      short8_t af[4], bfr[4];
      #pragma unroll
      for (int mi = 0; mi < 4; ++mi)
        af[mi] = *reinterpret_cast<const short8_t*>(&lds_a[wr*64 + mi*16 + lr][ks + kg*8]);
      #pragma unroll
      for (int ni = 0; ni < 4; ++ni)
        bfr[ni] = *reinterpret_cast<const short8_t*>(&lds_b[wc*64 + ni*16 + lr][ks + kg*8]);
      #pragma unroll
      for (int mi = 0; mi < 4; ++mi)
        #pragma unroll
        for (int ni = 0; ni < 4; ++ni)
          acc[mi][ni] = __builtin_amdgcn_mfma_f32_16x16x32_bf16(af[mi], bfr[ni], acc[mi][ni], 0, 0, 0);
    }
    __syncthreads();
  }
  float w2v[4], sbv[4];
  #pragma unroll
  for (int ni = 0; ni < 4; ++ni){
    const int h = n0 + wc*64 + ni*16 + lr;
    w2v[ni] = w2[h];
    float s = 0.f;
    #pragma unroll
    for (int ds = 0; ds < 8; ++ds) s += sbp[(size_t)(ds*32 + b)*512 + h];
    sbv[ni] = s;
  }
  float* red = reinterpret_cast<float*>(&lds_a[0][0]);
  #pragma unroll
  for (int mi = 0; mi < 4; ++mi){
    #pragma unroll
    for (int j = 0; j < 4; ++j){
      float v = 0.f;
      #pragma unroll
      for (int ni = 0; ni < 4; ++ni)
        v += tanh_cheap(tanh_cheap(acc[mi][ni][j] + sbv[ni])) * w2v[ni];
      v += __shfl_xor(v, 1); v += __shfl_xor(v, 2);
      v += __shfl_xor(v, 4); v += __shfl_xor(v, 8);
      if (lr == 0){
        const int rloc = wr*64 + mi*16 + kg*4 + j;
        red[wc*128 + rloc] = v;
      }
    }
  }
  __syncthreads();
  if (t < 128) plog[(size_t)nt*65536 + m0 + t] = red[t] + red[128 + t];
}

// ---------------------------------------------------------------- K2: softmax stats
__global__ __launch_bounds__(256) void k2_softmax(const float* __restrict__ plog,
                                                  const float* __restrict__ mask,
                                                  float* __restrict__ out_logit,
                                                  float* __restrict__ mz,
                                                  int npart){
  const int b = blockIdx.x, t = threadIdx.x;
  float l[8]; float mx = -3.4e38f;
  #pragma unroll
  for (int i = 0; i < 8; ++i){
    const size_t idx = (size_t)b*2048 + t + i*256;
    float v = 0.f;
    for (int p = 0; p < npart; ++p) v += plog[(size_t)p*65536 + idx];
    v -= NEG_BIG * (1.0f - mask[idx]);
    l[i] = v;
    out_logit[idx] = v;
    mx = fmaxf(mx, v);
  }
  __shared__ float red[8];
  const int wid = t >> 6, lane = t & 63;
  #pragma unroll
  for (int off = 1; off < 64; off <<= 1) mx = fmaxf(mx, __shfl_xor(mx, off));
  if (lane == 0) red[wid] = mx;
  __syncthreads();
  mx = fmaxf(fmaxf(red[0], red[1]), fmaxf(red[2], red[3]));
  float zs = 0.f;
  #pragma unroll
  for (int i = 0; i < 8; ++i) zs += __expf(l[i] - mx);
  #pragma unroll
  for (int off = 1; off < 64; off <<= 1) zs += __shfl_xor(zs, off);
  if (lane == 0) red[4 + wid] = zs;
  __syncthreads();
  if (t == 0){ mz[b*2] = mx; mz[b*2+1] = red[4]+red[5]+red[6]+red[7]; }
}

// ---------------------------------------------------------------- K3 fast: pool from bf16
__global__ __launch_bounds__(256) void k3_pool_bf(const unsigned short* __restrict__ inb,
                                                  const float* __restrict__ logit,
                                                  const float* __restrict__ mz,
                                                  float* __restrict__ pool){
  const int b = blockIdx.x >> 4, sc = blockIdx.x & 15;
  const int t = threadIdx.x;
  __shared__ float p[128];
  const float m = mz[b*2], invZ = 1.0f / mz[b*2+1];
  if (t < 128) p[t] = __expf(logit[(size_t)b*2048 + sc*128 + t] - m) * invZ;
  __syncthreads();
  const int half = t >> 7, cw = t & 127;
  float a0=0.f,a1=0.f,a2=0.f,a3=0.f;
  const unsigned short* base = inb + ((size_t)b*2048 + sc*128 + half)*512 + cw*4;
  #pragma unroll 4
  for (int i = 0; i < 64; ++i){
    const ushort4 v = *reinterpret_cast<const ushort4*>(base + (size_t)i*1024);
    const float pv = p[half + 2*i];
    a0 += pv*bf2f(v.x); a1 += pv*bf2f(v.y); a2 += pv*bf2f(v.z); a3 += pv*bf2f(v.w);
  }
  float4 o = {a0,a1,a2,a3};
  *reinterpret_cast<float4*>(pool + (size_t)blockIdx.x*1024 + half*512 + cw*4) = o;
}

// ---------------------------------------------------------------- K3 fallback: fp32 input
__global__ __launch_bounds__(256) void k3_pool_f32(const float* __restrict__ input,
                                                   const float* __restrict__ logit,
                                                   const float* __restrict__ mz,
                                                   float* __restrict__ pool){
  const int b = blockIdx.x >> 4, sc = blockIdx.x & 15;
  const int t = threadIdx.x;
  __shared__ float p[128];
  const float m = mz[b*2], invZ = 1.0f / mz[b*2+1];
  if (t < 128) p[t] = __expf(logit[(size_t)b*2048 + sc*128 + t] - m) * invZ;
  __syncthreads();
  float a0 = 0.f, a1 = 0.f;
  const float* base = input + ((size_t)b*2048 + sc*128)*512 + 2*t;
  #pragma unroll 4
  for (int i = 0; i < 128; ++i){
    const float2 v = *reinterpret_cast<const float2*>(base + (size_t)i*512);
    a0 += p[i]*v.x; a1 += p[i]*v.y;
  }
  pool[(size_t)blockIdx.x*512 + 2*t]     = a0;
  pool[(size_t)blockIdx.x*512 + 2*t + 1] = a1;
}

// ---------------------------------------------------------------- K4: reduce partials
__global__ __launch_bounds__(256) void k4_reduce(const float* __restrict__ pool,
                                                 float* __restrict__ out_pooled,
                                                 int nchunks){
  const int tg = blockIdx.x*256 + threadIdx.x;  // 0..16383
  const int b = tg >> 9, d = tg & 511;
  float s = 0.f;
  for (int c = 0; c < nchunks; ++c) s += pool[((size_t)b*nchunks + c)*512 + d];
  out_pooled[tg] = s;
}

// ---------------------------------------------------------------- launch
extern "C" void kernel_launch(void* const* d_in, const int* in_sizes, int n_in,
                              void* d_out, int out_size, void* d_ws, size_t ws_size,
                              hipStream_t stream){
  const float* input = (const float*)d_in[0];
  const float* state = (const float*)d_in[1];
  const float* mask  = (const float*)d_in[2];
  const float* W1    = (const float*)d_in[3];
  const float* w2    = (const float*)d_in[4];

  float* out_pooled = (float*)d_out;
  float* out_logit  = (float*)d_out + 16384;

  char* ws = (char*)d_ws;
  const size_t O_INB = 0;                    // 64 MB
  const size_t O_SBP = 67108864;             // 512 KB (8 x 32 x 512 f32)
  const size_t O_W1X = O_SBP + 524288;       // 512 KB
  const size_t O_PLG = O_W1X + 524288;       // 1 MB
  const size_t O_MZ  = O_PLG + 1048576;      // 256 B
  const size_t O_PL  = O_MZ  + 256;          // 2 MB
  const size_t NEED_FAST = O_PL + 2097152;

  if (ws_size >= NEED_FAST){
    unsigned short* inb  = (unsigned short*)(ws + O_INB);
    float*          sbp  = (float*)(ws + O_SBP);
    unsigned short* w1xt = (unsigned short*)(ws + O_W1X);
    float*          plog = (float*)(ws + O_PLG);
    float*          mz   = (float*)(ws + O_MZ);
    float*          pool = (float*)(ws + O_PL);

    k0_all      <<<2368, 256, 0, stream>>>(input, state, W1, inb, sbp, w1xt, 2048);
    k1_gemm_8ph <<<512,  512, 0, stream>>>(inb, w1xt, sbp, w2, plog);
    k2_softmax  <<<32,   256, 0, stream>>>(plog, mask, out_logit, mz, 2);
    k3_pool_bf  <<<512,  256, 0, stream>>>(inb, out_logit, mz, pool);
    k4_reduce   <<<64,   256, 0, stream>>>(pool, out_pooled, 32);
  } else {
    float*          sbp  = (float*)(ws);                                   // 512 KB
    unsigned short* w1xt = (unsigned short*)(ws + 524288);                 // 512 KB
    float*          plog = (float*)(ws + 1048576);                         // 1 MB
    float*          mz   = (float*)(ws + 2097152);                         // 256 B
    float*          pool = (float*)(ws + 2097408);                         // 1 MB

    k0_all    <<<320,  256, 0, stream>>>(nullptr, state, W1, nullptr, sbp, w1xt, 0);
    k1_gemm_fb<<<2048, 256, 0, stream>>>(input, w1xt, sbp, w2, plog);
    k2_softmax<<<32,   256, 0, stream>>>(plog, mask, out_logit, mz, 4);
    k3_pool_f32<<<512, 256, 0, stream>>>(input, out_logit, mz, pool);
    k4_reduce <<<64,   256, 0, stream>>>(pool, out_pooled, 16);
  }
}

// Round 15
// 97.586 us; speedup vs baseline: 1.4890x; 1.2009x over previous
//
#include <hip/hip_runtime.h>
#include <cstdint>
#include <cstddef>

// Problem: B=32, S=2048, D=512, H=512
//   sb[b,h]   = state @ W1[:D]
//   h         = tanh(tanh(sb + input@W1[D:]))   <-- DOUBLE tanh (reference quirk)
//   logit[b,s]= sum_h h * w2[h]  - 1e30*(1-mask)
//   p = softmax over S;  pooled[b,d] = sum_s p*input
// Outputs: pooled (16384 f32) ++ logit (65536 f32)
//
// r15: r14 architecture (fp32-A staged raw via gload_lds, cvt at ds_read time),
// with the ONE bug fixed: k4_reduce must sum 32 chunks/batch at (b*32+c)*512
// (k3 writes 16 sc-blocks x 2 half-partials per batch). r14's k4 summed a
// wrong 16-chunk window -> pooled mixed batches (absmax 0.15); logit path OK.

#define NEG_BIG 1e30f

typedef __attribute__((ext_vector_type(8))) short short8_t;   // 8 x bf16
typedef __attribute__((ext_vector_type(4))) float f32x4;

__device__ inline unsigned short f2bf(float f){
  union { float f; unsigned int u; } v; v.f = f;
  unsigned int r = v.u + 0x7fffu + ((v.u >> 16) & 1u);   // RNE
  return (unsigned short)(r >> 16);
}
// tanh via 1 - 2/(1+e^{2x}): exp overflow -> inf -> rcp -> 0 -> +1; underflow -> -1.
__device__ inline float tanh_cheap(float x){
  return 1.0f - 2.0f*__builtin_amdgcn_rcpf(1.0f + __expf(2.0f*x));
}

typedef __attribute__((address_space(1))) const unsigned int g_u32;
typedef __attribute__((address_space(3))) unsigned int l_u32;
__device__ inline void gload16(const void* g, unsigned short* l){
  __builtin_amdgcn_global_load_lds((g_u32*)g, (l_u32*)l, 16, 0, 0);
}

// ---------------------------------------------------------------- K0: prep (tiny)
// blocks 0..63   : w1xt[h][k] = bf16(W1[512+k][h])   (transpose)
// blocks 64..319 : sbp[ds][b][h] partial state@W1s
__global__ __launch_bounds__(256) void k0_prep(const float* __restrict__ state,
                                               const float* __restrict__ W1,
                                               float* __restrict__ sbp,
                                               unsigned short* __restrict__ w1xt){
  const int bid = blockIdx.x, t = threadIdx.x;
  if (bid < 64) {
    const int k0 = (bid >> 3) * 64, h0 = (bid & 7) * 64;
    __shared__ float tile[64][65];
    const int c = t & 63, r0 = t >> 6;
    #pragma unroll
    for (int i = 0; i < 16; ++i){
      int r = r0 + 4*i;
      tile[r][c] = W1[(size_t)(512 + k0 + r)*512 + h0 + c];
    }
    __syncthreads();
    #pragma unroll
    for (int i = 0; i < 16; ++i){
      int r = r0 + 4*i;
      w1xt[(size_t)(h0 + r)*512 + k0 + c] = f2bf(tile[c][r]);
    }
  } else {
    const int idx = bid - 64;               // 0..255
    const int b = idx >> 3, ds = idx & 7;
    __shared__ float stl[64];
    if (t < 64) stl[t] = state[b*512 + ds*64 + t];
    __syncthreads();
    float acc0 = 0.f, acc1 = 0.f;
    #pragma unroll 8
    for (int i = 0; i < 64; ++i){
      const float w = stl[i];
      acc0 += w * W1[(size_t)(ds*64 + i)*512 + t];
      acc1 += w * W1[(size_t)(ds*64 + i)*512 + t + 256];
    }
    sbp[(size_t)(ds*32 + b)*512 + t]       = acc0;
    sbp[(size_t)(ds*32 + b)*512 + t + 256] = acc1;
  }
}

// ---------------------------------------------------------------- K1: 256x256 GEMM, fp32-A in LDS
// 512 thr (8 waves 2Mx4N, wave-tile 128x64), BK=32, 16 K-tiles, 2 phases each.
// LDS 96KB: A-f32 2x32KB @0, B-bf16 2x16KB @byte 65536. Swizzle (both sides, rule #21):
//   A: 8 chunks/row(128B), phys = c ^ (row&7);  B: 4 chunks/row(64B), phys = c ^ (row&3).
// Phase q0: READ_A(all 8 mi, f32->cvt_pk->bf16) + READ_B(nh0); stage B(kt+1).
// Phase q1: READ_B(nh1) (af held in regs);       stage A(kt+2).
// Region safety: A-buf read ONLY at q0 -> A(kt+2) stage at kt q1 is after q0-end-barrier;
// B-buf read q0+q1 -> B(kt+1) stage at kt q0 is after (kt-1) q1-end-barrier.
// vmcnt ledger @ kt q1-end: outstanding = B(kt+1)[2] + A(kt+2)[4] + prior A(kt+1)[4]
//   -> vmcnt(4) drains A(kt+1)+B(kt+1) exactly. Tail: kt=14 -> vmcnt(0); kt=15 none.
__global__ __launch_bounds__(512, 1) void k1_gemm_f32a(const float* __restrict__ input,
                                                       const unsigned short* __restrict__ w1xt,
                                                       const float* __restrict__ sbp,
                                                       const float* __restrict__ w2,
                                                       float* __restrict__ plog){
  __shared__ unsigned short lds[49152];   // 96 KB

  const int orig = blockIdx.x;            // 512 blocks, bijective XCD swizzle (512%8==0)
  const int xcd = orig & 7, qq = orig >> 3;
  const int mtile = xcd*32 + (qq >> 1);
  const int nt = qq & 1;                  // nt 0/1 of same mtile adjacent -> A L2 reuse
  const int m0 = mtile*256, n0 = nt*256;
  const int b = m0 >> 11;

  const int t = threadIdx.x;
  const int lane = t & 63, wid = t >> 6;
  const int wr = wid >> 2, wcn = wid & 3;
  const int lr = lane & 15, kg = lane >> 4;
  const int l7 = lr & 7;

  // --- staging sources (inverse-swizzled per-lane global addr; LDS dest linear)
  const int arow = t >> 3;                               // 0..63 within 64-row span
  const int ainv = (t & 7) ^ ((t >> 3) & 7);             // A src 16B-chunk (f32: *4 cols)
  const float* gA = input + (size_t)(m0 + arow)*512 + ainv*4;
  const int brow = t >> 2;                               // 0..127 within 128-row span
  const int binv = (t & 3) ^ ((t >> 2) & 3);             // B src 16B-chunk (bf16: *8 cols)
  const unsigned short* gBp = w1xt + (size_t)(n0 + brow)*512 + binv*8;

  f32x4 acc[8][4];
  #pragma unroll
  for (int mi = 0; mi < 8; ++mi)
    #pragma unroll
    for (int ni = 0; ni < 4; ++ni) acc[mi][ni] = (f32x4){0.f,0.f,0.f,0.f};

  short8_t af[8], bf[2];

  // A tile = 256 rows x 32 f32 = 32 KB = 4 gloads (8KB each: 64 rows)
#define STAGE_A(KT) do{ \
    const float* gs_ = gA + (KT)*32; \
    const unsigned db_ = (unsigned)((((KT)&1)*16384) + wid*512); \
    gload16(gs_,             &lds[db_]); \
    gload16(gs_ +  64*512,   &lds[db_ + 4096]); \
    gload16(gs_ + 128*512,   &lds[db_ + 8192]); \
    gload16(gs_ + 192*512,   &lds[db_ + 12288]); }while(0)

  // B tile = 256 rows x 32 bf16 = 16 KB = 2 gloads (128 rows each)
#define STAGE_B(KT) do{ \
    const unsigned short* gs_ = gBp + (KT)*32; \
    const unsigned db_ = (unsigned)(32768 + (((KT)&1)*8192) + wid*512); \
    gload16(gs_,            &lds[db_]); \
    gload16(gs_ + 128*512,  &lds[db_ + 4096]); }while(0)

  // read 8 mi fragments: 2x ds_read_b128 (f32) + 4x cvt_pk -> bf16 short8
#define READ_A_ALL(KT) do{ \
    const unsigned ab_ = (unsigned)(((KT)&1)*16384); \
    _Pragma("unroll") for (int mi = 0; mi < 8; ++mi){ \
      const unsigned r_ = (unsigned)(wr*128 + mi*16 + lr); \
      f32x4 lo_ = *(const f32x4*)&lds[ab_ + r_*64 + (unsigned)(((2*kg    ) ^ l7)*8)]; \
      f32x4 hi_ = *(const f32x4*)&lds[ab_ + r_*64 + (unsigned)(((2*kg + 1) ^ l7)*8)]; \
      union { short8_t s; unsigned u[4]; } pk_; \
      asm("v_cvt_pk_bf16_f32 %0, %1, %2" : "=v"(pk_.u[0]) : "v"(lo_[0]), "v"(lo_[1])); \
      asm("v_cvt_pk_bf16_f32 %0, %1, %2" : "=v"(pk_.u[1]) : "v"(lo_[2]), "v"(lo_[3])); \
      asm("v_cvt_pk_bf16_f32 %0, %1, %2" : "=v"(pk_.u[2]) : "v"(hi_[0]), "v"(hi_[1])); \
      asm("v_cvt_pk_bf16_f32 %0, %1, %2" : "=v"(pk_.u[3]) : "v"(hi_[2]), "v"(hi_[3])); \
      af[mi] = pk_.s; \
      if (mi == 3) __builtin_amdgcn_sched_barrier(0); /* cap transient reg pressure */ \
    } }while(0)

#define READ_B(NH, KT) do{ \
    const unsigned bb_ = 32768u + (unsigned)(((KT)&1)*8192); \
    _Pragma("unroll") for (int nn = 0; nn < 2; ++nn){ \
      const unsigned rw_ = (unsigned)(wcn*64 + ((NH)*2+nn)*16 + lr); \
      bf[nn] = *(const short8_t*)&lds[bb_ + rw_*32 + (unsigned)((kg ^ (lr & 3))*8)]; } }while(0)

#define MFMA16(NH) do{ \
    __builtin_amdgcn_s_setprio(1); \
    _Pragma("unroll") for (int mi = 0; mi < 8; ++mi) \
      _Pragma("unroll") for (int nn = 0; nn < 2; ++nn) \
        acc[mi][(NH)*2+nn] = __builtin_amdgcn_mfma_f32_16x16x32_bf16(af[mi], bf[nn], acc[mi][(NH)*2+nn], 0,0,0); \
    __builtin_amdgcn_s_setprio(0); }while(0)

  // prologue: A(0) B(0) A(1) = 10 loads; vmcnt(4) -> kt0 landed, A(1) in flight
  STAGE_A(0); STAGE_B(0); STAGE_A(1);
  asm volatile("s_waitcnt vmcnt(4)" ::: "memory");
  __builtin_amdgcn_s_barrier();

  #pragma unroll
  for (int kt = 0; kt < 16; ++kt){
    // ---- q0
    READ_A_ALL(kt);
    READ_B(0, kt);
    if (kt + 1 < 16) STAGE_B(kt + 1);
    __builtin_amdgcn_s_barrier();
    asm volatile("s_waitcnt lgkmcnt(0)" ::: "memory");
    __builtin_amdgcn_sched_barrier(0);
    MFMA16(0);
    __builtin_amdgcn_s_barrier();
    // ---- q1
    READ_B(1, kt);
    if (kt + 2 < 16) STAGE_A(kt + 2);
    __builtin_amdgcn_s_barrier();
    asm volatile("s_waitcnt lgkmcnt(0)" ::: "memory");
    __builtin_amdgcn_sched_barrier(0);
    MFMA16(1);
    if (kt + 1 < 16){
      if (kt + 2 < 16) asm volatile("s_waitcnt vmcnt(4)" ::: "memory");
      else             asm volatile("s_waitcnt vmcnt(0)" ::: "memory");
    }
    __builtin_amdgcn_s_barrier();
  }
#undef STAGE_A
#undef STAGE_B
#undef READ_A_ALL
#undef READ_B
#undef MFMA16

  // epilogue: tanh(tanh(acc + sb)) * w2, reduce over this block's 256 h-cols
  float w2v[4], sbv[4];
  #pragma unroll
  for (int ni = 0; ni < 4; ++ni){
    const int h = n0 + wcn*64 + ni*16 + lr;
    w2v[ni] = w2[h];
    float s = 0.f;
    #pragma unroll
    for (int ds = 0; ds < 8; ++ds) s += sbp[(size_t)(ds*32 + b)*512 + h];
    sbv[ni] = s;
  }
  float* red = reinterpret_cast<float*>(&lds[0]);   // 1024 floats (post-barrier reuse)
  #pragma unroll
  for (int mi = 0; mi < 8; ++mi){
    #pragma unroll
    for (int j = 0; j < 4; ++j){
      float v = 0.f;
      #pragma unroll
      for (int ni = 0; ni < 4; ++ni)
        v += tanh_cheap(tanh_cheap(acc[mi][ni][j] + sbv[ni])) * w2v[ni];
      v += __shfl_xor(v, 1); v += __shfl_xor(v, 2);
      v += __shfl_xor(v, 4); v += __shfl_xor(v, 8);   // sum 16 cols
      if (lr == 0)
        red[wcn*256 + wr*128 + mi*16 + kg*4 + j] = v; // C/D row=(lane>>4)*4+j
    }
  }
  __syncthreads();
  if (t < 256)
    plog[(size_t)nt*65536 + m0 + t] = red[t] + red[256+t] + red[512+t] + red[768+t];
}

// ---------------------------------------------------------------- K2: softmax stats (2 partials)
__global__ __launch_bounds__(256) void k2_softmax(const float* __restrict__ plog,
                                                  const float* __restrict__ mask,
                                                  float* __restrict__ out_logit,
                                                  float* __restrict__ mz){
  const int b = blockIdx.x, t = threadIdx.x;
  float l[8]; float mx = -3.4e38f;
  #pragma unroll
  for (int i = 0; i < 8; ++i){
    const size_t idx = (size_t)b*2048 + t + i*256;
    float v = plog[idx] + plog[65536 + idx];
    v -= NEG_BIG * (1.0f - mask[idx]);
    l[i] = v;
    out_logit[idx] = v;
    mx = fmaxf(mx, v);
  }
  __shared__ float red[8];
  const int wid = t >> 6, lane = t & 63;
  #pragma unroll
  for (int off = 1; off < 64; off <<= 1) mx = fmaxf(mx, __shfl_xor(mx, off));
  if (lane == 0) red[wid] = mx;
  __syncthreads();
  mx = fmaxf(fmaxf(red[0], red[1]), fmaxf(red[2], red[3]));
  float zs = 0.f;
  #pragma unroll
  for (int i = 0; i < 8; ++i) zs += __expf(l[i] - mx);
  #pragma unroll
  for (int off = 1; off < 64; off <<= 1) zs += __shfl_xor(zs, off);
  if (lane == 0) red[4 + wid] = zs;
  __syncthreads();
  if (t == 0){ mz[b*2] = mx; mz[b*2+1] = red[4]+red[5]+red[6]+red[7]; }
}

// ---------------------------------------------------------------- K3: pooled partials (fp32, float4/thread)
__global__ __launch_bounds__(256) void k3_pool(const float* __restrict__ input,
                                               const float* __restrict__ logit,
                                               const float* __restrict__ mz,
                                               float* __restrict__ pool){
  const int b = blockIdx.x >> 4, sc = blockIdx.x & 15;
  const int t = threadIdx.x;
  __shared__ float p[128];
  const float m = mz[b*2], invZ = 1.0f / mz[b*2+1];
  if (t < 128) p[t] = __expf(logit[(size_t)b*2048 + sc*128 + t] - m) * invZ;
  __syncthreads();
  const int half = t >> 7, cw = t & 127;
  float a0=0.f,a1=0.f,a2=0.f,a3=0.f;
  const float* base = input + ((size_t)b*2048 + sc*128 + half)*512 + cw*4;
  #pragma unroll 4
  for (int i = 0; i < 64; ++i){
    const float4 v = *reinterpret_cast<const float4*>(base + (size_t)i*1024);
    const float pv = p[half + 2*i];
    a0 += pv*v.x; a1 += pv*v.y; a2 += pv*v.z; a3 += pv*v.w;
  }
  float4 o = {a0,a1,a2,a3};
  *reinterpret_cast<float4*>(pool + (size_t)blockIdx.x*1024 + half*512 + cw*4) = o;
}

// ---------------------------------------------------------------- K4: reduce partials
// pool layout: batch b owns 32 chunks of 512 floats (16 sc-blocks x 2 halves):
//   chunk index c = sc*2 + half, float = (b*32 + c)*512 + d.   (r14 bug: used 16)
__global__ __launch_bounds__(256) void k4_reduce(const float* __restrict__ pool,
                                                 float* __restrict__ out_pooled){
  const int tg = blockIdx.x*256 + threadIdx.x;  // 0..16383
  const int b = tg >> 9, d = tg & 511;
  float s = 0.f;
  #pragma unroll
  for (int c = 0; c < 32; ++c) s += pool[((size_t)b*32 + c)*512 + d];
  out_pooled[tg] = s;
}

// ---------------------------------------------------------------- launch
extern "C" void kernel_launch(void* const* d_in, const int* in_sizes, int n_in,
                              void* d_out, int out_size, void* d_ws, size_t ws_size,
                              hipStream_t stream){
  const float* input = (const float*)d_in[0];
  const float* state = (const float*)d_in[1];
  const float* mask  = (const float*)d_in[2];
  const float* W1    = (const float*)d_in[3];
  const float* w2    = (const float*)d_in[4];

  float* out_pooled = (float*)d_out;
  float* out_logit  = (float*)d_out + 16384;

  char* ws = (char*)d_ws;
  float*          sbp  = (float*)(ws);                   // 512 KB
  unsigned short* w1xt = (unsigned short*)(ws + 524288); // 512 KB
  float*          plog = (float*)(ws + 1048576);         // 512 KB (2 partials)
  float*          mz   = (float*)(ws + 1572864);         // 256 B
  float*          pool = (float*)(ws + 1573120);         // 2 MB
  (void)ws_size; (void)in_sizes; (void)n_in; (void)out_size;

  k0_prep     <<<320, 256, 0, stream>>>(state, W1, sbp, w1xt);
  k1_gemm_f32a<<<512, 512, 0, stream>>>(input, w1xt, sbp, w2, plog);
  k2_softmax  <<<32,  256, 0, stream>>>(plog, mask, out_logit, mz);
  k3_pool     <<<512, 256, 0, stream>>>(input, out_logit, mz, pool);
  k4_reduce   <<<64,  256, 0, stream>>>(pool, out_pooled);
}